// Round 6
// baseline (127.246 us; speedup 1.0000x reference)
//
#include <hip/hip_runtime.h>
#include <hip/hip_fp16.h>

// Problem constants (from reference).
#define N_GENOMES 30000
#define N_GENES   240000
#define N_SAMPLES 128
#define N_SEQS    80000
#define CAP       32   // max genes per seq (Poisson mean 3; realized max ~15; CAP=32 safe)

#define SCATTER_BLOCKS  ((N_GENES + 255) / 256)        // 938
#define COMPRESS_BLOCKS ((N_GENOMES * 32) / 256)       // 3750 (exact)

// Native vector types so __builtin_nontemporal_load/store accept them.
typedef float        f32x4 __attribute__((ext_vector_type(4)));
typedef unsigned int u32x4 __attribute__((ext_vector_type(4)));

// ---------------------------------------------------------------------------
// Fused prep kernel.
// Blocks [0, SCATTER_BLOCKS): bucket-scatter genes by seq id with PACKED 4B
//   records: genome (15 bits) | pos quantized to 17 bits (pos*131072 exact in
//   fp32; truncation <= 2^-17).
// Blocks [SCATTER_BLOCKS, ...): compress A/B to fp16 interleaved per quad:
//   {a+1 x4, b x4} = 16B per (genome, quad). A/B are read-once -> nontemporal
//   loads, so L2 retention favors the AB16/bucket working set accum re-reads.
// ---------------------------------------------------------------------------
__global__ __launch_bounds__(256) void prep_kernel(
    const float* __restrict__ A,
    const float* __restrict__ B,
    const float* __restrict__ pos,
    const int*   __restrict__ genome_idx,
    const int*   __restrict__ seq_idx,
    int*          __restrict__ cnt,     // N_SEQS, zeroed
    unsigned int* __restrict__ bucket,  // N_SEQS * CAP packed records
    float4*       __restrict__ AB16)    // N_GENOMES*32 x 16B interleaved fp16
{
    int b = blockIdx.x;
    if (b < SCATTER_BLOCKS) {
        int gene = b * 256 + threadIdx.x;
        if (gene >= N_GENES) return;
        int   s = seq_idx[gene];
        int   g = genome_idx[gene];
        float p = pos[gene];
        unsigned int q   = (unsigned int)(p * 131072.0f);   // exact mul, trunc
        unsigned int rec = (unsigned int)g | (q << 15);
        int slot = atomicAdd(&cnt[s], 1);
        if (slot < CAP) bucket[s * CAP + slot] = rec;
    } else {
        int idx = (b - SCATTER_BLOCKS) * 256 + threadIdx.x; // genome*32+quad
        f32x4 a  = __builtin_nontemporal_load((const f32x4*)A + idx);
        f32x4 bb = __builtin_nontemporal_load((const f32x4*)B + idx);
        __half2 h[4];
        h[0] = __floats2half2_rn(a.x + 1.0f, a.y + 1.0f);   // fold the +1 here
        h[1] = __floats2half2_rn(a.z + 1.0f, a.w + 1.0f);
        h[2] = __floats2half2_rn(bb.x, bb.y);
        h[3] = __floats2half2_rn(bb.z, bb.w);
        AB16[idx] = *reinterpret_cast<float4*>(h);          // cached: accum re-reads
    }
}

// ---------------------------------------------------------------------------
// Accum kernel. One thread per (seq, quad); 32 lanes = one seq.
// 2-level dependent chain: {uint4 bucket-row load || cnt load} -> 4 AB16 row
// loads -> masked fp16-decode/exp/accumulate -> one nontemporal float4 store.
// Row loads do NOT wait on n: dead-slot poison (0xAAAAAAAA) decodes to a
// 15-bit genome index whose AB16 offset (< 16.8 MB) stays inside the 256 MiB
// workspace, and the contribution is masked by (j < n). Values from real rows
// are finite, so no NaN/Inf can leak through the mask.
// Every out element is written (n==0 -> zeros), so no out memset needed.
// ---------------------------------------------------------------------------
__global__ __launch_bounds__(256) void accum_kernel(
    const float4*       __restrict__ AB16,
    const int*          __restrict__ cnt,
    const unsigned int* __restrict__ bucket,
    float*              __restrict__ out)
{
    int idx  = blockIdx.x * blockDim.x + threadIdx.x;
    int seq  = idx >> 5;
    int quad = idx & 31;
    if (seq >= N_SEQS) return;   // grid is exact (80000*32/256); never taken

    const u32x4* bk4 = reinterpret_cast<const u32x4*>(bucket + seq * CAP); // 16B-aligned
    u32x4 r4 = bk4[0];           // issued immediately, independent of cnt
    int   n  = cnt[seq];         // issued in parallel with r4
    if (n > CAP) n = CAP;

    float4 acc = make_float4(0.f, 0.f, 0.f, 0.f);

    // Chunk 0 (covers 81.5% of non-empty seqs entirely).
    {
        unsigned int r[4] = { r4.x, r4.y, r4.z, r4.w };
        float4 raw[4];
        #pragma unroll
        for (int j = 0; j < 4; ++j)
            raw[j] = AB16[(r[j] & 0x7fffu) * 32 + quad];   // unmasked, in-ws
        #pragma unroll
        for (int j = 0; j < 4; ++j) {
            float p = (float)(r[j] >> 15) * (1.0f / 131072.0f);
            const __half2* hp = reinterpret_cast<const __half2*>(&raw[j]);
            float2 a01 = __half22float2(hp[0]);
            float2 a23 = __half22float2(hp[1]);
            float2 b01 = __half22float2(hp[2]);
            float2 b23 = __half22float2(hp[3]);
            if (j < n) {
                acc.x += __expf(a01.x - p * b01.x);        // +1 folded into a
                acc.y += __expf(a01.y - p * b01.y);
                acc.z += __expf(a23.x - p * b23.x);
                acc.w += __expf(a23.y - p * b23.y);
            }
        }
    }

    // Rare tail: n > 4 (18.5% of non-empty seqs), chunks of 4.
    if (n > 4) {
        for (int i0 = 4; i0 < n; i0 += 4) {
            u32x4 t4 = bk4[i0 >> 2];
            unsigned int r[4] = { t4.x, t4.y, t4.z, t4.w };
            float4 raw[4];
            #pragma unroll
            for (int j = 0; j < 4; ++j)
                raw[j] = AB16[(r[j] & 0x7fffu) * 32 + quad];
            #pragma unroll
            for (int j = 0; j < 4; ++j) {
                float p = (float)(r[j] >> 15) * (1.0f / 131072.0f);
                const __half2* hp = reinterpret_cast<const __half2*>(&raw[j]);
                float2 a01 = __half22float2(hp[0]);
                float2 a23 = __half22float2(hp[1]);
                float2 b01 = __half22float2(hp[2]);
                float2 b23 = __half22float2(hp[3]);
                if (i0 + j < n) {
                    acc.x += __expf(a01.x - p * b01.x);
                    acc.y += __expf(a01.y - p * b01.y);
                    acc.z += __expf(a23.x - p * b23.x);
                    acc.w += __expf(a23.y - p * b23.y);
                }
            }
        }
    }

    // Out is written once and never re-read -> nontemporal (don't evict AB16).
    f32x4 o = { acc.x, acc.y, acc.z, acc.w };
    __builtin_nontemporal_store(o, (f32x4*)out + seq * 32 + quad);
}

extern "C" void kernel_launch(void* const* d_in, const int* in_sizes, int n_in,
                              void* d_out, int out_size, void* d_ws, size_t ws_size,
                              hipStream_t stream) {
    const float* A    = (const float*)d_in[0];
    const float* B    = (const float*)d_in[1];
    const float* pos  = (const float*)d_in[2];
    const int*   gidx = (const int*)d_in[3];
    const int*   sidx = (const int*)d_in[4];
    float*       out  = (float*)d_out;

    // Workspace layout (256 MiB available, ~26 MB used):
    //   [0, 15,360,000)            AB16: 960000 float4 (16B-aligned)
    //   [15,360,000, 15,680,000)   cnt: N_SEQS ints
    //   [15,680,000, 25,920,000)   bucket: N_SEQS*CAP uints (16B-aligned)
    char*         ws     = (char*)d_ws;
    float4*       AB16   = (float4*)ws;
    int*          cnt    = (int*)(ws + (size_t)N_GENOMES * 32 * 16);
    unsigned int* bucket = (unsigned int*)(cnt + N_SEQS);

    // d_ws is re-poisoned 0xAA before every launch; zero the counters only.
    hipMemsetAsync(cnt, 0, N_SEQS * sizeof(int), stream);

    prep_kernel<<<SCATTER_BLOCKS + COMPRESS_BLOCKS, 256, 0, stream>>>(
        A, B, pos, gidx, sidx, cnt, bucket, AB16);

    const int total = N_SEQS * 32;   // 2,560,000 threads, exact grid
    accum_kernel<<<total / 256, 256, 0, stream>>>(
        AB16, cnt, bucket, out);
}

// Round 7
// 126.493 us; speedup vs baseline: 1.0060x; 1.0060x over previous
//
#include <hip/hip_runtime.h>
#include <hip/hip_fp16.h>

// Problem constants (from reference).
#define N_GENOMES 30000
#define N_GENES   240000
#define N_SAMPLES 128
#define N_SEQS    80000
#define CAP       32   // max genes per seq (Poisson mean 3; realized max ~15; CAP=32 safe)

#define SCATTER_BLOCKS  ((N_GENES + 255) / 256)        // 938
#define COMPRESS_BLOCKS ((N_GENOMES * 32) / 256)       // 3750 (exact)

// Native vector types so __builtin_nontemporal_load/store accept them.
typedef float        f32x4 __attribute__((ext_vector_type(4)));
typedef unsigned int u32x4 __attribute__((ext_vector_type(4)));

// ---------------------------------------------------------------------------
// Fused prep kernel.
// Blocks [0, SCATTER_BLOCKS): bucket-scatter genes by seq id with PACKED 4B
//   records: genome (15 bits) | pos quantized to 17 bits (pos*131072 exact in
//   fp32; truncation <= 2^-17).
// Blocks [SCATTER_BLOCKS, ...): compress A/B to fp16 interleaved per quad:
//   {a+1 x4, b x4} = 16B per (genome, quad). A/B are read-once -> nontemporal
//   loads, so L2 retention favors the AB16/bucket working set accum re-reads.
// ---------------------------------------------------------------------------
__global__ __launch_bounds__(256) void prep_kernel(
    const float* __restrict__ A,
    const float* __restrict__ B,
    const float* __restrict__ pos,
    const int*   __restrict__ genome_idx,
    const int*   __restrict__ seq_idx,
    int*          __restrict__ cnt,     // N_SEQS, zeroed
    unsigned int* __restrict__ bucket,  // N_SEQS * CAP packed records, zeroed
    float4*       __restrict__ AB16)    // N_GENOMES*32 x 16B interleaved fp16
{
    int b = blockIdx.x;
    if (b < SCATTER_BLOCKS) {
        int gene = b * 256 + threadIdx.x;
        if (gene >= N_GENES) return;
        int   s = seq_idx[gene];
        int   g = genome_idx[gene];
        float p = pos[gene];
        unsigned int q   = (unsigned int)(p * 131072.0f);   // exact mul, trunc
        unsigned int rec = (unsigned int)g | (q << 15);
        int slot = atomicAdd(&cnt[s], 1);
        if (slot < CAP) bucket[s * CAP + slot] = rec;
    } else {
        int idx = (b - SCATTER_BLOCKS) * 256 + threadIdx.x; // genome*32+quad
        f32x4 a  = __builtin_nontemporal_load((const f32x4*)A + idx);
        f32x4 bb = __builtin_nontemporal_load((const f32x4*)B + idx);
        __half2 h[4];
        h[0] = __floats2half2_rn(a.x + 1.0f, a.y + 1.0f);   // fold the +1 here
        h[1] = __floats2half2_rn(a.z + 1.0f, a.w + 1.0f);
        h[2] = __floats2half2_rn(bb.x, bb.y);
        h[3] = __floats2half2_rn(bb.z, bb.w);
        AB16[idx] = *reinterpret_cast<float4*>(h);          // cached: accum re-reads
    }
}

// ---------------------------------------------------------------------------
// Accum kernel. One thread per (seq, quad); 32 lanes = one seq.
// 2-level dependent chain: {uint4 bucket-row load || cnt load} -> 4 AB16 row
// loads -> masked fp16-decode/exp/accumulate -> one nontemporal float4 store.
// Row loads do NOT wait on n: bucket is ZERO-FILLED, so dead slots decode to
// record 0 = genome 0, p=0 -> row 0, which is L1-hot after first touch (no
// junk cold-row traffic, unlike reading workspace poison). The (j < n) mask
// excludes row 0's contribution from the accumulate.
// Every out element is written (n==0 -> zeros), so no out memset needed.
// ---------------------------------------------------------------------------
__global__ __launch_bounds__(256) void accum_kernel(
    const float4*       __restrict__ AB16,
    const int*          __restrict__ cnt,
    const unsigned int* __restrict__ bucket,
    float*              __restrict__ out)
{
    int idx  = blockIdx.x * blockDim.x + threadIdx.x;
    int seq  = idx >> 5;
    int quad = idx & 31;
    if (seq >= N_SEQS) return;   // grid is exact (80000*32/256); never taken

    const u32x4* bk4 = reinterpret_cast<const u32x4*>(bucket + seq * CAP); // 16B-aligned
    u32x4 r4 = bk4[0];           // issued immediately, independent of cnt
    int   n  = cnt[seq];         // issued in parallel with r4
    if (n > CAP) n = CAP;

    float4 acc = make_float4(0.f, 0.f, 0.f, 0.f);

    // Chunk 0 (covers 81.5% of non-empty seqs entirely).
    {
        unsigned int r[4] = { r4.x, r4.y, r4.z, r4.w };
        float4 raw[4];
        #pragma unroll
        for (int j = 0; j < 4; ++j)
            raw[j] = AB16[(r[j] & 0x7fffu) * 32 + quad];   // dead slots -> row 0 (hot)
        #pragma unroll
        for (int j = 0; j < 4; ++j) {
            float p = (float)(r[j] >> 15) * (1.0f / 131072.0f);
            const __half2* hp = reinterpret_cast<const __half2*>(&raw[j]);
            float2 a01 = __half22float2(hp[0]);
            float2 a23 = __half22float2(hp[1]);
            float2 b01 = __half22float2(hp[2]);
            float2 b23 = __half22float2(hp[3]);
            if (j < n) {
                acc.x += __expf(a01.x - p * b01.x);        // +1 folded into a
                acc.y += __expf(a01.y - p * b01.y);
                acc.z += __expf(a23.x - p * b23.x);
                acc.w += __expf(a23.y - p * b23.y);
            }
        }
    }

    // Rare tail: n > 4 (18.5% of non-empty seqs), chunks of 4.
    if (n > 4) {
        for (int i0 = 4; i0 < n; i0 += 4) {
            u32x4 t4 = bk4[i0 >> 2];
            unsigned int r[4] = { t4.x, t4.y, t4.z, t4.w };
            float4 raw[4];
            #pragma unroll
            for (int j = 0; j < 4; ++j)
                raw[j] = AB16[(r[j] & 0x7fffu) * 32 + quad];  // dead -> row 0
            #pragma unroll
            for (int j = 0; j < 4; ++j) {
                float p = (float)(r[j] >> 15) * (1.0f / 131072.0f);
                const __half2* hp = reinterpret_cast<const __half2*>(&raw[j]);
                float2 a01 = __half22float2(hp[0]);
                float2 a23 = __half22float2(hp[1]);
                float2 b01 = __half22float2(hp[2]);
                float2 b23 = __half22float2(hp[3]);
                if (i0 + j < n) {
                    acc.x += __expf(a01.x - p * b01.x);
                    acc.y += __expf(a01.y - p * b01.y);
                    acc.z += __expf(a23.x - p * b23.x);
                    acc.w += __expf(a23.y - p * b23.y);
                }
            }
        }
    }

    // Out is written once and never re-read -> nontemporal (don't evict AB16).
    f32x4 o = { acc.x, acc.y, acc.z, acc.w };
    __builtin_nontemporal_store(o, (f32x4*)out + seq * 32 + quad);
}

extern "C" void kernel_launch(void* const* d_in, const int* in_sizes, int n_in,
                              void* d_out, int out_size, void* d_ws, size_t ws_size,
                              hipStream_t stream) {
    const float* A    = (const float*)d_in[0];
    const float* B    = (const float*)d_in[1];
    const float* pos  = (const float*)d_in[2];
    const int*   gidx = (const int*)d_in[3];
    const int*   sidx = (const int*)d_in[4];
    float*       out  = (float*)d_out;

    // Workspace layout (256 MiB available, ~26 MB used):
    //   [0, 15,360,000)            AB16: 960000 float4 (16B-aligned)
    //   [15,360,000, 15,680,000)   cnt: N_SEQS ints
    //   [15,680,000, 25,920,000)   bucket: N_SEQS*CAP uints (16B-aligned)
    char*         ws     = (char*)d_ws;
    float4*       AB16   = (float4*)ws;
    int*          cnt    = (int*)(ws + (size_t)N_GENOMES * 32 * 16);
    unsigned int* bucket = (unsigned int*)(cnt + N_SEQS);

    // Zero cnt AND bucket in one contiguous memset (10.56 MB, ~1.8 us):
    // zero-filled dead bucket slots decode to row 0 (L1-hot) in accum.
    hipMemsetAsync(cnt, 0, (size_t)(N_SEQS + N_SEQS * CAP) * sizeof(int), stream);

    prep_kernel<<<SCATTER_BLOCKS + COMPRESS_BLOCKS, 256, 0, stream>>>(
        A, B, pos, gidx, sidx, cnt, bucket, AB16);

    const int total = N_SEQS * 32;   // 2,560,000 threads, exact grid
    accum_kernel<<<total / 256, 256, 0, stream>>>(
        AB16, cnt, bucket, out);
}